// Round 3
// baseline (411.289 us; speedup 1.0000x reference)
//
#include <hip/hip_runtime.h>
#include <hip/hip_bf16.h>
#include <stdint.h>

#define BATCH   16384
#define IN_DIM  4096
#define OUT_DIM 64
#define KI      64              // input dims per LDS chunk
#define KCH     (3*KI)          // 192 k_eff per chunk
#define NCHUNK  (IN_DIM/KI)     // 64
#define SPLITK  4
#define CPB     (NCHUNK/SPLITK) // 16 chunks per block
#define MTILES  (BATCH/64)      // 256
#define CHW     (OUT_DIM*KCH)   // 12288 shorts per weight chunk (24 KB)

typedef __attribute__((ext_vector_type(8))) short   short8;
typedef __attribute__((ext_vector_type(4))) float   floatx4;
typedef __attribute__((ext_vector_type(4))) uint32_t uintx4;

static __device__ __forceinline__ unsigned short f2bf(float f) {
    union { float f; uint32_t u; } v; v.f = f;
    uint32_t r = v.u + 0x7FFFu + ((v.u >> 16) & 1u);   // RNE
    return (unsigned short)(r >> 16);
}

// pack two floats -> two bf16 (RNE) in one dword: {lo -> bits[15:0], hi -> bits[31:16]}
static __device__ __forceinline__ uint32_t pk2bf(float lo, float hi) {
    union { float f; uint32_t u; } a, b;
    a.f = lo; b.f = hi;
    uint32_t ra = a.u + 0x7FFFu + ((a.u >> 16) & 1u);
    uint32_t rb = b.u + 0x7FFFu + ((b.u >> 16) & 1u);
    return (ra >> 16) | (rb & 0xFFFF0000u);
}

// Closed-form degree-3 Cox-de Boor basis for knots [-1,-.5,0,.5,1,1]:
//  B0: |x|<0.5 : 4|x|^3-4x^2+2/3 ; 0.5<=|x|<1 : (4/3)(1-|x|)^3 ; else 0
//  B1: [-0.5,0): (4/3)x^3+2x^2+x+1/6 ; [0,0.5): -(14/3)x^3+2x^2+x+1/6
//      [0.5,1): (22x^3-48x^2+30x-4)/3 ; else 0
static __device__ __forceinline__ void kan_features(float xv, float& b0, float& b1, float& sl) {
    float ax = fabsf(xv);
    float a2 = ax*ax;
    float om = 1.0f - ax;
    float inner = __builtin_fmaf(__builtin_fmaf(4.0f, ax, -4.0f), a2, (2.0f/3.0f));
    float outer = (om*om) * (om * (4.0f/3.0f));
    b0 = (ax < 0.5f) ? inner : outer;
    b0 = (ax < 1.0f) ? b0 : 0.0f;
    float c3  = (xv < 0.0f) ? (4.0f/3.0f) : (-14.0f/3.0f);
    float mid = __builtin_fmaf(__builtin_fmaf(__builtin_fmaf(c3, xv, 2.0f), xv, 1.0f), xv, (1.0f/6.0f));
    float hi  = __builtin_fmaf(__builtin_fmaf(__builtin_fmaf(22.0f, xv, -48.0f), xv, 30.0f), xv, -4.0f) * (1.0f/3.0f);
    b1 = (xv < 0.5f) ? mid : hi;
    b1 = (xv >= -0.5f && xv < 1.0f) ? b1 : 0.0f;
    float e = __expf(-xv);
    sl = xv * __builtin_amdgcn_rcpf(1.0f + e);
}

// Swizzled pack: chunk ci holds 64 j-rows x 24 granules (16B each).
// granule(j, t, ig) lives at linear index  j*24 + ((t*8 + ig) ^ (j&7)),
// content = 8 consecutive il (il = ig*8..ig*8+7):
//   t=0: c[i][j][0]*ws[i][j], t=1: c[i][j][1]*ws[i][j], t=2: wb[i][j]
__global__ __launch_bounds__(256) void kan_prep(
        const float* __restrict__ c, const float* __restrict__ ws,
        const float* __restrict__ wb, unsigned short* __restrict__ Wt) {
    int idx = blockIdx.x * 256 + threadIdx.x;     // 0..98303 = 192 rows * 512 i-groups
    int row = idx >> 9;                           // j*3+t, 0..191
    int i   = (idx & 511) << 3;                   // 8 consecutive input dims
    int j   = row / 3;
    int t   = row - j*3;
    int ci  = i >> 6, il0 = i & 63;
    unsigned short pk[8];
    #pragma unroll
    for (int e = 0; e < 8; e++) {
        int ii = i + e;
        float v;
        if (t < 2) v = c[(size_t)ii*(OUT_DIM*2) + j*2 + t] * ws[(size_t)ii*OUT_DIM + j];
        else       v = wb[(size_t)ii*OUT_DIM + j];
        pk[e] = f2bf(v);
    }
    uintx4 d;
    d[0] = pk[0] | ((uint32_t)pk[1] << 16);
    d[1] = pk[2] | ((uint32_t)pk[3] << 16);
    d[2] = pk[4] | ((uint32_t)pk[5] << 16);
    d[3] = pk[6] | ((uint32_t)pk[7] << 16);
    int g = j*24 + (((t << 3) | (il0 >> 3)) ^ (j & 7));
    *(uintx4*)(Wt + (size_t)ci*CHW + g*8) = d;
}

// Main GEMM: weights via async global->LDS (no VGPR staging), partials to pbuf.
// Partial layout: P[kh][mt][n][tid] as floatx4  (fully coalesced 16B/lane stores)
__global__ __launch_bounds__(256, 4) void kan_main_pre(
    const float* __restrict__ x, const unsigned short* __restrict__ Wt,
    float* __restrict__ pbuf)
{
    __shared__ unsigned short Bs[CHW];   // 24 KB, swizzled granule layout

    const int tid  = threadIdx.x;
    const int wave = tid >> 6;
    const int lane = tid & 63;
    const int m    = lane & 15;
    const int q    = lane >> 4;
    const int mt   = blockIdx.x & (MTILES - 1);
    const int kh   = blockIdx.x >> 8;                // SPLITK group
    const int row0 = mt * 64;
    const int r    = row0 + wave*16 + m;             // this lane's A-row
    const float* xrow = x + (size_t)r * IN_DIM;

    floatx4 acc[4] = {};

    // preload x for first chunk
    const int i00 = kh * CPB * KI;
    floatx4 xv[4];
    xv[0] = *(const floatx4*)(xrow + i00 + q*8);
    xv[1] = *(const floatx4*)(xrow + i00 + q*8 + 4);
    xv[2] = *(const floatx4*)(xrow + i00 + 32 + q*8);
    xv[3] = *(const floatx4*)(xrow + i00 + 32 + q*8 + 4);

    for (int cc = 0; cc < CPB; cc++) {
        const int ci = kh * CPB + cc;
        const int i0 = ci * KI;

        // ---- prefetch NEXT chunk's x (HBM); drained at barrier1, hidden by features ----
        const int inx = (cc + 1 < CPB) ? (i0 + KI) : i0;
        floatx4 xvn[4];
        xvn[0] = *(const floatx4*)(xrow + inx + q*8);
        xvn[1] = *(const floatx4*)(xrow + inx + q*8 + 4);
        xvn[2] = *(const floatx4*)(xrow + inx + 32 + q*8);
        xvn[3] = *(const floatx4*)(xrow + inx + 32 + q*8 + 4);

        // ---- features from xv (pure VALU, ~1300 cy: hides the prefetch) ----
        uintx4 afu[6];   // ksteps: 0,1=B0(i 0..31,32..63) 2,3=B1 4,5=silu
        #pragma unroll
        for (int g = 0; g < 2; g++) {
            #pragma unroll
            for (int w = 0; w < 4; w++) {
                float v0 = xv[g*2 + (w >> 1)][(w & 1)*2 + 0];
                float v1 = xv[g*2 + (w >> 1)][(w & 1)*2 + 1];
                float b00, b10, sl0, b01, b11, sl1;
                kan_features(v0, b00, b10, sl0);
                kan_features(v1, b01, b11, sl1);
                afu[0 + g][w] = pk2bf(b00, b01);
                afu[2 + g][w] = pk2bf(b10, b11);
                afu[4 + g][w] = pk2bf(sl0, sl1);
            }
        }

        __syncthreads();   // previous chunk's LDS consumers done

        // ---- async global->LDS weight staging: 1536 granules, wave-linear ----
        const unsigned short* gW = Wt + (size_t)ci * CHW;
        #pragma unroll
        for (int p = 0; p < 6; p++) {
            int g0 = p*256 + wave*64;
            __builtin_amdgcn_global_load_lds(
                (__attribute__((address_space(1))) void*)(gW + (size_t)(g0 + lane)*8),
                (__attribute__((address_space(3))) void*)(Bs + (size_t)g0*8),
                16, 0, 0);
        }

        __syncthreads();   // drains vmcnt -> staging visible

        #pragma unroll
        for (int s = 0; s < 6; s++) {
            const int kb = (s >> 1)*8 + (s & 1)*4 + q;   // granule row index
            #pragma unroll
            for (int n = 0; n < 4; n++) {
                const int j = n*16 + m;                   // output col
                short8 bf = *(const short8*)&Bs[j*KCH + ((kb ^ (j & 7)) << 3)];
                acc[n] = __builtin_amdgcn_mfma_f32_16x16x32_bf16(
                    __builtin_bit_cast(short8, afu[s]), bf, acc[n], 0, 0, 0);
            }
        }

        xv[0] = xvn[0]; xv[1] = xvn[1]; xv[2] = xvn[2]; xv[3] = xvn[3];
    }

    // ---- coalesced partial store (no atomics) ----
    float* pb = pbuf + (((size_t)kh*MTILES + mt)*4)*256*4;
    #pragma unroll
    for (int n = 0; n < 4; n++)
        *(floatx4*)(pb + ((size_t)n*256 + tid)*4) = acc[n];
}

// Sum SPLITK partials -> out.  C/D layout: col=lane&15, row=quad*4+reg.
__global__ __launch_bounds__(256) void kan_reduce(
    const float* __restrict__ pbuf, float* __restrict__ out)
{
    const int mt   = blockIdx.x;
    const int tid  = threadIdx.x;
    const int wave = tid >> 6;
    const int lane = tid & 63;
    const int m    = lane & 15;
    const int q    = lane >> 4;
    #pragma unroll
    for (int n = 0; n < 4; n++) {
        floatx4 s = {};
        #pragma unroll
        for (int p = 0; p < SPLITK; p++) {
            floatx4 v = *(const floatx4*)(pbuf +
                ((((size_t)p*MTILES + mt)*4 + n)*256 + tid)*4);
            s += v;
        }
        #pragma unroll
        for (int reg = 0; reg < 4; reg++) {
            int orow = mt*64 + wave*16 + q*4 + reg;
            out[(size_t)orow*OUT_DIM + n*16 + m] = s[reg];
        }
    }
}

// ---------------- fallback (tiny ws): R2 path with atomics ----------------
__global__ __launch_bounds__(256, 4) void kan_main_fb(
    const float* __restrict__ x, const float* __restrict__ c,
    const float* __restrict__ ws, const float* __restrict__ wb,
    float* __restrict__ out)
{
    __shared__ unsigned short Bs[CHW];
    const int tid  = threadIdx.x;
    const int wave = tid >> 6;
    const int lane = tid & 63;
    const int m    = lane & 15;
    const int q    = lane >> 4;
    const int mt   = blockIdx.x & (MTILES - 1);
    const int kh   = blockIdx.x >> 8;
    const int row0 = mt * 64;
    const int r    = row0 + wave*16 + m;
    const float* xrow = x + (size_t)r * IN_DIM;
    floatx4 acc[4] = {};
    for (int cc = 0; cc < CPB; cc++) {
        const int i0 = (kh * CPB + cc) * KI;
        floatx4 xv[4];
        xv[0] = *(const floatx4*)(xrow + i0 + q*8);
        xv[1] = *(const floatx4*)(xrow + i0 + q*8 + 4);
        xv[2] = *(const floatx4*)(xrow + i0 + 32 + q*8);
        xv[3] = *(const floatx4*)(xrow + i0 + 32 + q*8 + 4);
        uintx4 afu[6];
        #pragma unroll
        for (int g = 0; g < 2; g++) {
            #pragma unroll
            for (int w = 0; w < 4; w++) {
                float v0 = xv[g*2 + (w >> 1)][(w & 1)*2 + 0];
                float v1 = xv[g*2 + (w >> 1)][(w & 1)*2 + 1];
                float b00, b10, sl0, b01, b11, sl1;
                kan_features(v0, b00, b10, sl0);
                kan_features(v1, b01, b11, sl1);
                afu[0 + g][w] = pk2bf(b00, b01);
                afu[2 + g][w] = pk2bf(b10, b11);
                afu[4 + g][w] = pk2bf(sl0, sl1);
            }
        }
        __syncthreads();
        #pragma unroll
        for (int p = 0; p < 16; p++) {
            int idx = tid + p*256;
            int j = idx & 63, i = idx >> 6;
            int gi = i0 + i;
            const float* cp = c + ((size_t)gi*OUT_DIM + j)*2;
            float c0 = cp[0], c1 = cp[1];
            float sw = ws[(size_t)gi*OUT_DIM + j];
            float b  = wb[(size_t)gi*OUT_DIM + j];
            int jx = j & 7;
            Bs[j*KCH + ((0*8 + (i>>3)) ^ jx)*8 + (i&7)] = f2bf(c0*sw);
            Bs[j*KCH + ((1*8 + (i>>3)) ^ jx)*8 + (i&7)] = f2bf(c1*sw);
            Bs[j*KCH + ((2*8 + (i>>3)) ^ jx)*8 + (i&7)] = f2bf(b);
        }
        __syncthreads();
        #pragma unroll
        for (int s = 0; s < 6; s++) {
            const int kb = (s >> 1)*8 + (s & 1)*4 + q;
            #pragma unroll
            for (int n = 0; n < 4; n++) {
                const int j = n*16 + m;
                short8 bf = *(const short8*)&Bs[j*KCH + ((kb ^ (j & 7)) << 3)];
                acc[n] = __builtin_amdgcn_mfma_f32_16x16x32_bf16(
                    __builtin_bit_cast(short8, afu[s]), bf, acc[n], 0, 0, 0);
            }
        }
    }
    #pragma unroll
    for (int n = 0; n < 4; n++)
        #pragma unroll
        for (int reg = 0; reg < 4; reg++) {
            int orow = row0 + wave*16 + q*4 + reg;
            atomicAdd(&out[(size_t)orow*OUT_DIM + n*16 + m], acc[n][reg]);
        }
}

extern "C" void kernel_launch(void* const* d_in, const int* in_sizes, int n_in,
                              void* d_out, int out_size, void* d_ws, size_t ws_size,
                              hipStream_t stream) {
    const float* x  = (const float*)d_in[0];
    const float* c  = (const float*)d_in[1];
    const float* ws = (const float*)d_in[2];
    const float* wb = (const float*)d_in[3];
    float* out = (float*)d_out;

    const size_t part_bytes = (size_t)SPLITK * BATCH * OUT_DIM * sizeof(float); // 16 MB
    const size_t wt_bytes   = (size_t)NCHUNK * CHW * sizeof(unsigned short);    // 1.5 MB
    if (ws_size >= part_bytes + wt_bytes) {
        float* pbuf = (float*)d_ws;
        unsigned short* Wt = (unsigned short*)((char*)d_ws + part_bytes);
        kan_prep<<<384, 256, 0, stream>>>(c, ws, wb, Wt);
        kan_main_pre<<<MTILES * SPLITK, 256, 0, stream>>>(x, Wt, pbuf);
        kan_reduce<<<MTILES, 256, 0, stream>>>(pbuf, out);
    } else {
        hipMemsetAsync(d_out, 0, (size_t)out_size * sizeof(float), stream);
        kan_main_fb<<<MTILES * SPLITK, 256, 0, stream>>>(x, c, ws, wb, out);
    }
}

// Round 4
// 402.032 us; speedup vs baseline: 1.0230x; 1.0230x over previous
//
#include <hip/hip_runtime.h>
#include <hip/hip_bf16.h>
#include <stdint.h>

#define BATCH   16384
#define IN_DIM  4096
#define OUT_DIM 64
#define MTILES  (BATCH/64)      // 256

// ---- main path: KI=32 chunks, double-buffered, SPLITK=8 ----
#define KI2     32
#define NCH2    (IN_DIM/KI2)    // 128 chunks
#define SPLITK  8
#define CPB2    (NCH2/SPLITK)   // 16 chunks per block
#define GRAN2   (OUT_DIM*13)    // 832 granules/chunk (13/row: 12 data + 1 pad)
#define CH2W    (GRAN2*8)       // 6656 shorts per chunk (13 KB, pad baked in)

// ---- fallback path (R3 structure, KI=64, SPLITK=4) ----
#define KI      64
#define KCH     (3*KI)          // 192
#define NCHUNK  (IN_DIM/KI)     // 64
#define FCPB    16
#define CHW     (OUT_DIM*KCH)   // 12288

typedef __attribute__((ext_vector_type(8))) short   short8;
typedef __attribute__((ext_vector_type(4))) float   floatx4;
typedef __attribute__((ext_vector_type(4))) uint32_t uintx4;

static __device__ __forceinline__ unsigned short f2bf(float f) {
    union { float f; uint32_t u; } v; v.f = f;
    uint32_t r = v.u + 0x7FFFu + ((v.u >> 16) & 1u);   // RNE
    return (unsigned short)(r >> 16);
}

// pack two floats -> two bf16 (RNE) in one dword
static __device__ __forceinline__ uint32_t pk2bf(float lo, float hi) {
    union { float f; uint32_t u; } a, b;
    a.f = lo; b.f = hi;
    uint32_t ra = a.u + 0x7FFFu + ((a.u >> 16) & 1u);
    uint32_t rb = b.u + 0x7FFFu + ((b.u >> 16) & 1u);
    return (ra >> 16) | (rb & 0xFFFF0000u);
}

// Degree-3 Cox-de Boor basis, knots [-1,-.5,0,.5,1,1], clamp-trick branchless-ish:
//  B0 via axc=min(|x|,1):  axc<.5: 4axc^3-4axc^2+2/3 ; else (4/3)(1-axc)^3  (0 at axc=1)
//  B1 via xc=med3(x,-.5,1): xc<.5: ((c3*xc+2)xc+1)xc+1/6 (c3 = x<0 ? 4/3 : -14/3)
//                           else (22xc^3-48xc^2+30xc-4)/3   (mid(-.5)=0, hi(1)=0)
static __device__ __forceinline__ void kan_features(float xv, float& b0, float& b1, float& sl) {
    float ax  = fabsf(xv);
    float axc = fminf(ax, 1.0f);
    float a2  = axc*axc;
    float om  = 1.0f - axc;
    float inner = __builtin_fmaf(__builtin_fmaf(4.0f, axc, -4.0f), a2, (2.0f/3.0f));
    float outer = (om*om) * (om * (4.0f/3.0f));
    b0 = (axc < 0.5f) ? inner : outer;
    float xc  = fminf(fmaxf(xv, -0.5f), 1.0f);        // v_med3
    float c3  = (xc < 0.0f) ? (4.0f/3.0f) : (-14.0f/3.0f);
    float mid = __builtin_fmaf(__builtin_fmaf(__builtin_fmaf(c3, xc, 2.0f), xc, 1.0f), xc, (1.0f/6.0f));
    float hi  = __builtin_fmaf(__builtin_fmaf(__builtin_fmaf(22.0f, xc, -48.0f), xc, 30.0f), xc, -4.0f) * (1.0f/3.0f);
    b1 = (xc < 0.5f) ? mid : hi;
    float e = __expf(-xv);
    sl = xv * __builtin_amdgcn_rcpf(1.0f + e);
}

// Pack weights, chunk-major, stride-13 granule rows (granule = 16 B = 8 il):
//   Wt[ci*CH2W + (j*13 + t*4 + ig)*8 + (il&7)]
//   t=0: c[i][j][0]*ws[i][j], t=1: c[i][j][1]*ws[i][j], t=2: wb[i][j]
__global__ __launch_bounds__(256) void kan_prep(
        const float* __restrict__ c, const float* __restrict__ ws,
        const float* __restrict__ wb, unsigned short* __restrict__ Wt) {
    int idx = blockIdx.x * 256 + threadIdx.x;     // 192 rows * 512 i-groups
    int row = idx >> 9;                           // j*3+t
    int i   = (idx & 511) << 3;                   // 8 consecutive input dims
    int j   = row / 3;
    int t   = row - j*3;
    int ci  = i >> 5;                             // 128 chunks of 32
    int ig  = (i & 31) >> 3;                      // granule within row-third
    unsigned short pk[8];
    #pragma unroll
    for (int e = 0; e < 8; e++) {
        int ii = i + e;
        float v;
        if (t < 2) v = c[(size_t)ii*(OUT_DIM*2) + j*2 + t] * ws[(size_t)ii*OUT_DIM + j];
        else       v = wb[(size_t)ii*OUT_DIM + j];
        pk[e] = f2bf(v);
    }
    uintx4 d;
    d[0] = pk[0] | ((uint32_t)pk[1] << 16);
    d[1] = pk[2] | ((uint32_t)pk[3] << 16);
    d[2] = pk[4] | ((uint32_t)pk[5] << 16);
    d[3] = pk[6] | ((uint32_t)pk[7] << 16);
    int g = j*13 + t*4 + ig;
    *(uintx4*)(Wt + (size_t)ci*CH2W + (size_t)g*8) = d;
}

// Main: double-buffered LDS, one barrier per chunk, partials to pbuf.
__global__ __launch_bounds__(256, 6) void kan_main_pre(
    const float* __restrict__ x, const unsigned short* __restrict__ Wt,
    float* __restrict__ pbuf)
{
    __shared__ unsigned short Bs[2][CH2W];   // 2 x 13 KB

    const int tid  = threadIdx.x;
    const int wave = tid >> 6;
    const int lane = tid & 63;
    const int m    = lane & 15;
    const int q    = lane >> 4;
    const int mt   = blockIdx.x & (MTILES - 1);
    const int kh   = blockIdx.x >> 8;                // SPLITK group 0..7
    const int row0 = mt * 64;
    const int r    = row0 + wave*16 + m;
    const float* xrow = x + (size_t)r * IN_DIM;
    const int ci0 = kh * CPB2;

    floatx4 acc[4] = {};

    // preload x for chunk 0
    floatx4 xv0 = *(const floatx4*)(xrow + ci0*KI2 + q*8);
    floatx4 xv1 = *(const floatx4*)(xrow + ci0*KI2 + q*8 + 4);

    // stage chunk 0 -> buffer 0 (832 granules, lane-linear DMA)
    {
        const unsigned short* gW = Wt + (size_t)ci0 * CH2W;
        #pragma unroll
        for (int p = 0; p < 3; p++) {
            int g0 = p*256 + wave*64;
            __builtin_amdgcn_global_load_lds(
                (__attribute__((address_space(1))) void*)(gW + (size_t)(g0 + lane)*8),
                (__attribute__((address_space(3))) void*)(&Bs[0][0] + (size_t)g0*8),
                16, 0, 0);
        }
        if (tid < 64)
            __builtin_amdgcn_global_load_lds(
                (__attribute__((address_space(1))) void*)(gW + (size_t)(768 + lane)*8),
                (__attribute__((address_space(3))) void*)(&Bs[0][0] + (size_t)768*8),
                16, 0, 0);
    }
    __syncthreads();

    for (int cc = 0; cc < CPB2; cc++) {
        const int buf = cc & 1;
        const int ci  = ci0 + cc;

        // ---- stage NEXT chunk into other buffer (drains at end barrier) ----
        if (cc + 1 < CPB2) {
            const unsigned short* gW = Wt + (size_t)(ci + 1) * CH2W;
            #pragma unroll
            for (int p = 0; p < 3; p++) {
                int g0 = p*256 + wave*64;
                __builtin_amdgcn_global_load_lds(
                    (__attribute__((address_space(1))) void*)(gW + (size_t)(g0 + lane)*8),
                    (__attribute__((address_space(3))) void*)(&Bs[buf^1][0] + (size_t)g0*8),
                    16, 0, 0);
            }
            if (tid < 64)
                __builtin_amdgcn_global_load_lds(
                    (__attribute__((address_space(1))) void*)(gW + (size_t)(768 + lane)*8),
                    (__attribute__((address_space(3))) void*)(&Bs[buf^1][0] + (size_t)768*8),
                    16, 0, 0);
        }

        // ---- prefetch next chunk's x (HBM; hidden by features+MFMA) ----
        const int inx = (cc + 1 < CPB2) ? (ci + 1)*KI2 : ci*KI2;
        floatx4 xn0 = *(const floatx4*)(xrow + inx + q*8);
        floatx4 xn1 = *(const floatx4*)(xrow + inx + q*8 + 4);

        // ---- features (pure VALU) ----
        uintx4 afu[3];   // t=0: B0, t=1: B1, t=2: silu ; 8 bf16 each
        #pragma unroll
        for (int w = 0; w < 4; w++) {
            float v0 = (w < 2) ? xv0[w*2]     : xv1[(w-2)*2];
            float v1 = (w < 2) ? xv0[w*2 + 1] : xv1[(w-2)*2 + 1];
            float b00, b10, s0, b01, b11, s1;
            kan_features(v0, b00, b10, s0);
            kan_features(v1, b01, b11, s1);
            afu[0][w] = pk2bf(b00, b01);
            afu[1][w] = pk2bf(b10, b11);
            afu[2][w] = pk2bf(s0, s1);
        }

        // ---- MFMA from current buffer ----
        #pragma unroll
        for (int t = 0; t < 3; t++) {
            #pragma unroll
            for (int n = 0; n < 4; n++) {
                const int j = n*16 + m;
                short8 bf = *(const short8*)&Bs[buf][(size_t)(j*13 + t*4 + q)*8];
                acc[n] = __builtin_amdgcn_mfma_f32_16x16x32_bf16(
                    __builtin_bit_cast(short8, afu[t]), bf, acc[n], 0, 0, 0);
            }
        }

        xv0 = xn0; xv1 = xn1;
        __syncthreads();   // buf readers done + buf^1 staging drained
    }

    // ---- coalesced partial store: P[kh][mt][n][tid] as floatx4 ----
    float* pb = pbuf + (((size_t)kh*MTILES + mt)*4)*1024;
    #pragma unroll
    for (int n = 0; n < 4; n++)
        *(floatx4*)(pb + ((size_t)n*256 + tid)*4) = acc[n];
}

// Sum SPLITK partials -> out.  C/D layout: col=lane&15, row=quad*4+reg.
__global__ __launch_bounds__(256) void kan_reduce(
    const float* __restrict__ pbuf, float* __restrict__ out)
{
    const int mt   = blockIdx.x;
    const int tid  = threadIdx.x;
    const int wave = tid >> 6;
    const int lane = tid & 63;
    const int m    = lane & 15;
    const int q    = lane >> 4;
    #pragma unroll
    for (int n = 0; n < 4; n++) {
        floatx4 s = {};
        #pragma unroll
        for (int p = 0; p < SPLITK; p++) {
            floatx4 v = *(const floatx4*)(pbuf +
                (((size_t)p*MTILES + mt)*4 + n)*1024 + (size_t)tid*4);
            s += v;
        }
        #pragma unroll
        for (int reg = 0; reg < 4; reg++) {
            int orow = mt*64 + wave*16 + q*4 + reg;
            out[(size_t)orow*OUT_DIM + n*16 + m] = s[reg];
        }
    }
}

// ---------------- fallback (tiny ws): R3 path with atomics ----------------
__global__ __launch_bounds__(256, 4) void kan_main_fb(
    const float* __restrict__ x, const float* __restrict__ c,
    const float* __restrict__ ws, const float* __restrict__ wb,
    float* __restrict__ out)
{
    __shared__ unsigned short Bsf[CHW];
    const int tid  = threadIdx.x;
    const int wave = tid >> 6;
    const int lane = tid & 63;
    const int m    = lane & 15;
    const int q    = lane >> 4;
    const int mt   = blockIdx.x & (MTILES - 1);
    const int kh   = blockIdx.x >> 8;
    const int row0 = mt * 64;
    const int r    = row0 + wave*16 + m;
    const float* xrow = x + (size_t)r * IN_DIM;
    floatx4 acc[4] = {};
    for (int cc = 0; cc < FCPB; cc++) {
        const int i0 = (kh * FCPB + cc) * KI;
        floatx4 xv[4];
        xv[0] = *(const floatx4*)(xrow + i0 + q*8);
        xv[1] = *(const floatx4*)(xrow + i0 + q*8 + 4);
        xv[2] = *(const floatx4*)(xrow + i0 + 32 + q*8);
        xv[3] = *(const floatx4*)(xrow + i0 + 32 + q*8 + 4);
        uintx4 afu[6];
        #pragma unroll
        for (int g = 0; g < 2; g++) {
            #pragma unroll
            for (int w = 0; w < 4; w++) {
                float v0 = xv[g*2 + (w >> 1)][(w & 1)*2 + 0];
                float v1 = xv[g*2 + (w >> 1)][(w & 1)*2 + 1];
                float b00, b10, sl0, b01, b11, sl1;
                kan_features(v0, b00, b10, sl0);
                kan_features(v1, b01, b11, sl1);
                afu[0 + g][w] = pk2bf(b00, b01);
                afu[2 + g][w] = pk2bf(b10, b11);
                afu[4 + g][w] = pk2bf(sl0, sl1);
            }
        }
        __syncthreads();
        #pragma unroll
        for (int p = 0; p < 16; p++) {
            int idx = tid + p*256;
            int j = idx & 63, i = idx >> 6;
            int gi = i0 + i;
            const float* cp = c + ((size_t)gi*OUT_DIM + j)*2;
            float c0 = cp[0], c1 = cp[1];
            float sw = ws[(size_t)gi*OUT_DIM + j];
            float b  = wb[(size_t)gi*OUT_DIM + j];
            int jx = j & 7;
            Bsf[j*KCH + ((0*8 + (i>>3)) ^ jx)*8 + (i&7)] = f2bf(c0*sw);
            Bsf[j*KCH + ((1*8 + (i>>3)) ^ jx)*8 + (i&7)] = f2bf(c1*sw);
            Bsf[j*KCH + ((2*8 + (i>>3)) ^ jx)*8 + (i&7)] = f2bf(b);
        }
        __syncthreads();
        #pragma unroll
        for (int s = 0; s < 6; s++) {
            const int kb = (s >> 1)*8 + (s & 1)*4 + q;
            #pragma unroll
            for (int n = 0; n < 4; n++) {
                const int j = n*16 + m;
                short8 bf = *(const short8*)&Bsf[j*KCH + ((kb ^ (j & 7)) << 3)];
                acc[n] = __builtin_amdgcn_mfma_f32_16x16x32_bf16(
                    __builtin_bit_cast(short8, afu[s]), bf, acc[n], 0, 0, 0);
            }
        }
    }
    #pragma unroll
    for (int n = 0; n < 4; n++)
        #pragma unroll
        for (int reg = 0; reg < 4; reg++) {
            int orow = row0 + wave*16 + q*4 + reg;
            atomicAdd(&out[(size_t)orow*OUT_DIM + n*16 + m], acc[n][reg]);
        }
}

extern "C" void kernel_launch(void* const* d_in, const int* in_sizes, int n_in,
                              void* d_out, int out_size, void* d_ws, size_t ws_size,
                              hipStream_t stream) {
    const float* x  = (const float*)d_in[0];
    const float* c  = (const float*)d_in[1];
    const float* ws = (const float*)d_in[2];
    const float* wb = (const float*)d_in[3];
    float* out = (float*)d_out;

    const size_t part_bytes = (size_t)SPLITK * BATCH * OUT_DIM * sizeof(float); // 32 MB
    const size_t wt_bytes   = (size_t)NCH2 * CH2W * sizeof(unsigned short);     // 1.7 MB
    if (ws_size >= part_bytes + wt_bytes) {
        float* pbuf = (float*)d_ws;
        unsigned short* Wt = (unsigned short*)((char*)d_ws + part_bytes);
        kan_prep<<<384, 256, 0, stream>>>(c, ws, wb, Wt);
        kan_main_pre<<<MTILES * SPLITK, 256, 0, stream>>>(x, Wt, pbuf);
        kan_reduce<<<MTILES, 256, 0, stream>>>(pbuf, out);
    } else {
        hipMemsetAsync(d_out, 0, (size_t)out_size * sizeof(float), stream);
        kan_main_fb<<<MTILES * 4, 256, 0, stream>>>(x, c, ws, wb, out);
    }
}